// Round 10
// baseline (1468.106 us; speedup 1.0000x reference)
//
#include <hip/hip_runtime.h>
#include <hip/hip_bf16.h>

// GRU-D layer: B=256, T=512, D=128, H=256, fp32.
// R10: quarter-split scan. R9 lessons: (1) 768thr x 128-dword U + working
// set > 512KB regfile -> parking inevitable; (2) gate-split idled waves
// (A: 8/12 busy, B: 4/12 -> 50% ceiling, measured 43%).
// New: 1024 thr = 256 cols x 4 k-quarters; thread owns 3 gate-columns for
// its quarter = 96 U dwords (+~30 working = ~126 <= 128 budget at
// launch_bounds(1024,4); 16 waves x 128 = exactly the file). ALL waves
// work in BOTH phases; 4 k-partials are in-wave (lane = q*16+i) ->
// butterfly shfl_xor(16,32) reduction, no LDS partials, 2 barriers/step.
// proj3 (fused f16 dot2 projection) unchanged from R8/R9.

static constexpr int Bb = 256;
static constexpr int Tt = 512;
static constexpr int Dd = 128;
static constexpr int Hh = 256;

typedef _Float16 half2_t __attribute__((ext_vector_type(2)));

__device__ __forceinline__ float dot2f(unsigned a, unsigned b, float c) {
  half2_t av, bv;
  __builtin_memcpy(&av, &a, 4);
  __builtin_memcpy(&bv, &b, 4);
#if __has_builtin(__builtin_amdgcn_fdot2)
  return __builtin_amdgcn_fdot2(av, bv, c, false);
#else
  return fmaf((float)av[1], (float)bv[1], fmaf((float)av[0], (float)bv[0], c));
#endif
}

__device__ __forceinline__ unsigned packh2(float lo, float hi) {
  half2_t hv;
  hv[0] = (_Float16)lo;
  hv[1] = (_Float16)hi;
  unsigned u;
  __builtin_memcpy(&u, &hv, 4);
  return u;
}

// ---------------------------------------------------------------------------
// Phase 1: fused projection (unchanged from R8/R9; validated)
// ---------------------------------------------------------------------------
__global__ __launch_bounds__(256) void proj3_kernel(
    const float* __restrict__ x,
    const float* __restrict__ Wz, const float* __restrict__ Wr,
    const float* __restrict__ Wh,
    const float* __restrict__ bz, const float* __restrict__ br,
    const float* __restrict__ bh,
    float* __restrict__ oz, float* __restrict__ orr, float* __restrict__ oh)
{
  __shared__ unsigned xP[64][64];
  __shared__ unsigned wP[8][256];

  const int tid = threadIdx.x;
  const int ty = tid >> 5;
  const int tx = tid & 31;
  const size_t brow = (size_t)blockIdx.x * 64;

  #pragma unroll
  for (int it = 0; it < 8; ++it) {
    int idx = it * 256 + tid;
    int row = idx & 63;
    int kq  = idx >> 6;
    float4 v = *(const float4*)(x + (brow + row) * Dd + kq * 4);
    xP[kq * 2 + 0][row] = packh2(v.x, v.y);
    xP[kq * 2 + 1][row] = packh2(v.z, v.w);
  }

  const float* Ws[3] = {Wz, Wr, Wh};
  const float* bs[3] = {bz, br, bh};
  float* os[3] = {oz, orr, oh};

  __syncthreads();

  for (int g = 0; g < 3; ++g) {
    float bv[8];
    *(float4*)&bv[0] = *(const float4*)(bs[g] + tx * 8);
    *(float4*)&bv[4] = *(const float4*)(bs[g] + tx * 8 + 4);

    float acc[8][8];
    #pragma unroll
    for (int i = 0; i < 8; ++i)
      #pragma unroll
      for (int jj = 0; jj < 8; ++jj) acc[i][jj] = 0.f;

    for (int s = 0; s < 8; ++s) {
      #pragma unroll
      for (int it = 0; it < 2; ++it) {
        int qq  = it * 256 + tid;
        int kkp = qq >> 6;
        int c4  = (qq & 63) * 4;
        const float* wr0 = Ws[g] + (size_t)((s * 8 + kkp) * 2) * Hh + c4;
        float4 wa = *(const float4*)wr0;
        float4 wb = *(const float4*)(wr0 + Hh);
        uint4 pk;
        pk.x = packh2(wa.x, wb.x);
        pk.y = packh2(wa.y, wb.y);
        pk.z = packh2(wa.z, wb.z);
        pk.w = packh2(wa.w, wb.w);
        *(uint4*)&wP[kkp][c4] = pk;
      }
      __syncthreads();

      #pragma unroll
      for (int kkp = 0; kkp < 8; ++kkp) {
        unsigned xv[8], wv[8];
        *(uint4*)&xv[0] = *(const uint4*)&xP[s * 8 + kkp][ty * 8];
        *(uint4*)&xv[4] = *(const uint4*)&xP[s * 8 + kkp][ty * 8 + 4];
        *(uint4*)&wv[0] = *(const uint4*)&wP[kkp][tx * 8];
        *(uint4*)&wv[4] = *(const uint4*)&wP[kkp][tx * 8 + 4];
        #pragma unroll
        for (int i = 0; i < 8; ++i)
          #pragma unroll
          for (int jj = 0; jj < 8; ++jj)
            acc[i][jj] = dot2f(xv[i], wv[jj], acc[i][jj]);
      }
      __syncthreads();
    }

    float* of = os[g];
    #pragma unroll
    for (int i = 0; i < 8; ++i) {
      size_t ro = (brow + (size_t)ty * 8 + i) * Hh + tx * 8;
      float4 a{acc[i][0] + bv[0], acc[i][1] + bv[1],
               acc[i][2] + bv[2], acc[i][3] + bv[3]};
      float4 c{acc[i][4] + bv[4], acc[i][5] + bv[5],
               acc[i][6] + bv[6], acc[i][7] + bv[7]};
      *(float4*)(of + ro) = a;
      *(float4*)(of + ro + 4) = c;
    }
  }
}

// ---------------------------------------------------------------------------
// Phase 2: quarter-split dot2 scan. 1 block = 1 batch, 1024 threads.
// Wave w: cols [16w,16w+16); lane = q*16+i, q = k-quarter, i = col-in-wave.
// Thread (j,q): Uz/Ur/Uh columns j over k in [64q,64q+64) = 96 f16-pair
// dwords. Per step: [A: z,r dots + butterfly + gates -> rhp] bar
//                   [B: h dots + butterfly + combine -> out, hdp] bar
// ---------------------------------------------------------------------------
__global__ __launch_bounds__(1024, 4) void gru_scan_q4(
    const float* __restrict__ xz, const float* __restrict__ xr,
    const float* __restrict__ hdecay,
    const float* __restrict__ Uz, const float* __restrict__ Ur,
    const float* __restrict__ Uh, float* __restrict__ out)
{
  const int tid  = threadIdx.x;
  const int w    = tid >> 6;
  const int lane = tid & 63;
  const int q    = lane >> 4;       // k-quarter 0..3
  const int i    = lane & 15;       // col within wave
  const int j    = w * 16 + i;      // output column 0..255
  const int b    = blockIdx.x;

  __shared__ unsigned hdp[128];     // f16x2 col-pairs of h_dec
  __shared__ unsigned rhp[128];     // f16x2 col-pairs of r*h_dec

  // ---- own U columns for k-quarter q: 3 x 32 dwords = 96 VGPRs ----
  unsigned uz[32], ur[32], uh[32];
  {
    const int kb = q * 64;
    const float* uzp = Uz + (size_t)kb * Hh + j;
    const float* urp = Ur + (size_t)kb * Hh + j;
    const float* uhp = Uh + (size_t)kb * Hh + j;
    #pragma unroll
    for (int m = 0; m < 32; ++m) {
      uz[m] = packh2(uzp[(size_t)(2 * m) * Hh], uzp[(size_t)(2 * m + 1) * Hh]);
      ur[m] = packh2(urp[(size_t)(2 * m) * Hh], urp[(size_t)(2 * m + 1) * Hh]);
      uh[m] = packh2(uhp[(size_t)(2 * m) * Hh], uhp[(size_t)(2 * m + 1) * Hh]);
    }
  }

  if (tid < 128) hdp[tid] = 0u;     // h0 = 0

  const size_t bbase = (size_t)b * Tt * Hh;
  const int    hbase = b * Tt;
  const float* pxz = xz + bbase + j;
  const float* pxr = xr + bbase + j;
  float*       pxh = out + bbase + j;   // xh lives in out; also h store target

  float hd = 0.f;                   // h_dec[j], replicated across q
  // prologue: t=0 inputs (all lanes, 4x q-redundant; L1/L2 absorb)
  float xz_c = pxz[0];
  float xr_c = pxr[0];
  float xh_c = pxh[0];
  float dec_n = hdecay[hbase + 1];
  __syncthreads();

  for (int t = 0; t < Tt; ++t) {
    // ---- prefetch t+1 (clamped; junk at t=Tt-1 never used) ----
    const int tp = (t + 1 < Tt) ? t + 1 : Tt - 1;
    const int to = tp * Hh;
    float xz_n = pxz[to];
    float xr_n = pxr[to];
    float xh_n = pxh[to];
    float dec_n2 = hdecay[hbase + ((t + 2 < Tt) ? t + 2 : Tt - 1)];

    // ---- phase A: z,r dots over own k-quarter ----
    float az0 = 0.f, az1 = 0.f, ar0 = 0.f, ar1 = 0.f;
    #pragma unroll
    for (int m8 = 0; m8 < 8; ++m8) {
      uint4 hp4 = *(const uint4*)&hdp[q * 32 + m8 * 4];
      const int mb = m8 * 4;
      az0 = dot2f(hp4.x, uz[mb + 0], az0);
      az1 = dot2f(hp4.y, uz[mb + 1], az1);
      az0 = dot2f(hp4.z, uz[mb + 2], az0);
      az1 = dot2f(hp4.w, uz[mb + 3], az1);
      ar0 = dot2f(hp4.x, ur[mb + 0], ar0);
      ar1 = dot2f(hp4.y, ur[mb + 1], ar1);
      ar0 = dot2f(hp4.z, ur[mb + 2], ar0);
      ar1 = dot2f(hp4.w, ur[mb + 3], ar1);
    }
    float sz = az0 + az1;
    float sr = ar0 + ar1;
    // butterfly over k-quarters (lanes ^16, ^32): all lanes get full sums
    sz += __shfl_xor(sz, 16, 64);
    sz += __shfl_xor(sz, 32, 64);
    sr += __shfl_xor(sr, 16, 64);
    sr += __shfl_xor(sr, 32, 64);
    const float zv = 1.f / (1.f + __expf(-(xz_c + sz)));
    const float rv = 1.f / (1.f + __expf(-(xr_c + sr)));
    float rh = rv * hd;
    float nbr = __shfl_xor(rh, 1, 64);      // partner col i^1
    if (q == 0 && (i & 1) == 0)
      rhp[w * 8 + (i >> 1)] = packh2(rh, nbr);
    __syncthreads();   // rhp visible; hdp reads done

    // ---- phase B: h dots over own k-quarter ----
    float ah0 = 0.f, ah1 = 0.f;
    #pragma unroll
    for (int m8 = 0; m8 < 8; ++m8) {
      uint4 rp4 = *(const uint4*)&rhp[q * 32 + m8 * 4];
      const int mb = m8 * 4;
      ah0 = dot2f(rp4.x, uh[mb + 0], ah0);
      ah1 = dot2f(rp4.y, uh[mb + 1], ah1);
      ah0 = dot2f(rp4.z, uh[mb + 2], ah0);
      ah1 = dot2f(rp4.w, uh[mb + 3], ah1);
    }
    float sh = ah0 + ah1;
    sh += __shfl_xor(sh, 16, 64);
    sh += __shfl_xor(sh, 32, 64);
    const float hs = xh_c + sh;
    const float ex = __expf(2.f * hs);      // tanh = 1 - 2/(e^{2x}+1)
    const float hp = 1.f - 2.f / (ex + 1.f);
    const float hn = (1.f - zv) * hd + zv * hp;
    if (q == 0) pxh[t * Hh] = hn;           // store h_t (16 lanes/wave)
    hd = dec_n * hn;                        // advance fp32 state (all lanes)
    float nbh = __shfl_xor(hd, 1, 64);
    if (q == 0 && (i & 1) == 0)
      hdp[w * 8 + (i >> 1)] = packh2(hd, nbh);
    xz_c = xz_n; xr_c = xr_n; xh_c = xh_n; dec_n = dec_n2;
    __syncthreads();   // hdp(t+1) visible
  }
}

// ---------------------------------------------------------------------------
extern "C" void kernel_launch(void* const* d_in, const int* in_sizes, int n_in,
                              void* d_out, int out_size, void* d_ws, size_t ws_size,
                              hipStream_t stream) {
  const float* x   = (const float*)d_in[0];
  const float* hdc = (const float*)d_in[1];
  const float* Wr  = (const float*)d_in[2];
  const float* Wz  = (const float*)d_in[3];
  const float* Wh  = (const float*)d_in[4];
  const float* Ur  = (const float*)d_in[5];
  const float* Uz  = (const float*)d_in[6];
  const float* Uh  = (const float*)d_in[7];
  const float* br  = (const float*)d_in[8];
  const float* bz  = (const float*)d_in[9];
  const float* bh  = (const float*)d_in[10];
  float* out = (float*)d_out;

  const size_t bth = (size_t)Bb * Tt * Hh;   // 33,554,432
  float* wsz = (float*)d_ws;
  float* wsr = wsz + bth;

  // fused projections: xz->ws, xr->ws, xh->out
  proj3_kernel<<<dim3(2048), dim3(256), 0, stream>>>(
      x, Wz, Wr, Wh, bz, br, bh, wsz, wsr, out);

  gru_scan_q4<<<dim3(Bb), dim3(1024), 0, stream>>>(
      wsz, wsr, hdc, Uz, Ur, Uh, out);
}